// Round 1
// baseline (129.308 us; speedup 1.0000x reference)
//
#include <hip/hip_runtime.h>
#include <math.h>

#define NATOMS   4096
#define NRBF     16
#define NHID     64
#define CUTOFF   5.0f
#define CUTOFF2  25.0f
// ETA = 0.5*(5.0-0.5)/16 = 0.140625 ; 1/(2*ETA^2)
#define INV_2ETA2 25.283950617283951f
#define PI_OVER_CUTOFF 0.62831853071795865f  // pi / 5

__global__ __launch_bounds__(256) void short_range_kernel(
    const float* __restrict__ pos,
    const float* __restrict__ centers,
    const float* __restrict__ W1, const float* __restrict__ b1,
    const float* __restrict__ W2, const float* __restrict__ b2,
    const float* __restrict__ W3, const float* __restrict__ b3,
    float* __restrict__ out)
{
    const int i    = blockIdx.x;
    const int tid  = threadIdx.x;
    const int lane = tid & 63;
    const int wave = tid >> 6;

    __shared__ float s_wsum[4][NRBF];
    __shared__ float s_feat[NRBF];
    __shared__ float s_h1[NHID];

    // centers in registers (uniform loads, L1-resident)
    float c[NRBF];
#pragma unroll
    for (int k = 0; k < NRBF; ++k) c[k] = centers[k];

    const float xi = pos[3 * i + 0];
    const float yi = pos[3 * i + 1];
    const float zi = pos[3 * i + 2];

    float facc[NRBF];
#pragma unroll
    for (int k = 0; k < NRBF; ++k) facc[k] = 0.0f;

    // each thread handles j = tid, tid+256, ... (16 iterations)
    for (int j = tid; j < NATOMS; j += 256) {
        const float dx = pos[3 * j + 0] - xi;
        const float dy = pos[3 * j + 1] - yi;
        const float dz = pos[3 * j + 2] - zi;
        const float sq = dx * dx + dy * dy + dz * dz;
        // ~0.7% of pairs pass: heavy path skipped for ~63% of waves via execz
        if (sq > 0.0f && sq < CUTOFF2) {
            const float dist = sqrtf(sq);
            const float w = 0.5f * (1.0f + __cosf(dist * PI_OVER_CUTOFF));
#pragma unroll
            for (int k = 0; k < NRBF; ++k) {
                const float d = dist - c[k];
                facc[k] += w * __expf(-(d * d) * INV_2ETA2);
            }
        }
    }

    // wave-level butterfly reduction of the 16 feature accumulators
#pragma unroll
    for (int k = 0; k < NRBF; ++k) {
        float v = facc[k];
#pragma unroll
        for (int off = 32; off > 0; off >>= 1) v += __shfl_xor(v, off, 64);
        facc[k] = v;
    }
    if (lane == 0) {
#pragma unroll
        for (int k = 0; k < NRBF; ++k) s_wsum[wave][k] = facc[k];
    }
    __syncthreads();
    if (tid < NRBF) {
        s_feat[tid] = s_wsum[0][tid] + s_wsum[1][tid] + s_wsum[2][tid] + s_wsum[3][tid];
    }
    __syncthreads();

    // ---- MLP epilogue on wave 0 ----
    // h1 = silu(feats @ W1 + b1)
    if (tid < NHID) {
        float h = b1[tid];
#pragma unroll
        for (int k = 0; k < NRBF; ++k) h += s_feat[k] * W1[k * NHID + tid];
        h = h / (1.0f + __expf(-h));   // silu
        s_h1[tid] = h;
    }
    __syncthreads();
    // h2 = silu(h1 @ W2 + b2); e = h2 . W3 + b3; atomicAdd into scalar out
    if (tid < NHID) {
        float h = b2[tid];
#pragma unroll 8
        for (int m = 0; m < NHID; ++m) h += s_h1[m] * W2[m * NHID + tid];
        h = h / (1.0f + __expf(-h));   // silu
        float e = h * W3[tid];
#pragma unroll
        for (int off = 32; off > 0; off >>= 1) e += __shfl_xor(e, off, 64);
        if (tid == 0) atomicAdd(out, e + b3[0]);
    }
}

extern "C" void kernel_launch(void* const* d_in, const int* in_sizes, int n_in,
                              void* d_out, int out_size, void* d_ws, size_t ws_size,
                              hipStream_t stream) {
    const float* pos     = (const float*)d_in[0];
    const float* centers = (const float*)d_in[1];
    const float* W1      = (const float*)d_in[2];
    const float* b1      = (const float*)d_in[3];
    const float* W2      = (const float*)d_in[4];
    const float* b2      = (const float*)d_in[5];
    const float* W3      = (const float*)d_in[6];
    const float* b3      = (const float*)d_in[7];
    float* out = (float*)d_out;

    // d_out is poisoned to 0xAA before every replay; zero it (capture-safe)
    hipMemsetAsync(out, 0, sizeof(float), stream);

    hipLaunchKernelGGL(short_range_kernel, dim3(NATOMS), dim3(256), 0, stream,
                       pos, centers, W1, b1, W2, b2, W3, b3, out);
}